// Round 17
// baseline (701.900 us; speedup 1.0000x reference)
//
#include <hip/hip_runtime.h>
#include <math.h>

#define DD 128
#define RING 8        // R16: 64-row bins -> small rings, 8-entry (32B) flush groups
#define MAXB 1600     // >= nb64 = ceil(N/64) = 1563
#define CAPSH 11      // 2048 entries per 64-row bin (avg ~1024, sigma ~32)
#define WCAP 248      // per-wave compacted list capacity (expected ~128)
#define NBIN_BLOCKS 256

using bf16x8 = __attribute__((ext_vector_type(8))) short;
using f32x4  = __attribute__((ext_vector_type(4))) float;

__device__ inline unsigned short f2bf(float f) {
    unsigned int u = __float_as_uint(f);
    unsigned int r = (u + 0x7fffu + ((u >> 16) & 1u)) >> 16;   // RNE
    return (unsigned short)r;
}
__device__ inline float bf2f(unsigned short h) {
    return __uint_as_float(((unsigned int)h) << 16);
}
__device__ inline float fsig(float v) {            // sigmoid via rcp (no v_div)
    return __builtin_amdgcn_rcpf(1.f + __expf(-v));
}
__device__ inline float ftanh(float v) {           // tanh via exp+rcp (no libm)
    float x = fminf(15.f, fmaxf(-15.f, v));
    float t = __expf(2.f * x);
    return (t - 1.f) * __builtin_amdgcn_rcpf(t + 1.f);
}

#define MFMA16(a, b, c) __builtin_amdgcn_mfma_f32_16x16x32_bf16((a), (b), (c), 0, 0, 0)

// Weights are stored PRE-SWIZZLED in wb (fragL order): staging = linear copy.
__device__ inline void copyW(float4* dst, const unsigned short* W, int tid) {
    const float4* s4 = reinterpret_cast<const float4*>(W);
#pragma unroll
    for (int it = 0; it < 8; ++it) dst[tid + it * 256] = s4[tid + it * 256];
}

// Fragment read from swizzled LDS matrix: row r, k-slice s.
__device__ inline bf16x8 fragL(const float4* lds, int lane, int s, int r) {
    float4 v = lds[r * 16 + (((s << 2) + (lane >> 4)) ^ (r & 15))];
    return __builtin_bit_cast(bf16x8, v);
}

__device__ inline bf16x8 fragG(const unsigned short* A, long row, int koff) {
    float4 v = *reinterpret_cast<const float4*>(A + row * DD + koff);
    return __builtin_bit_cast(bf16x8, v);
}

__device__ inline bf16x8 fragGF(const float* A, long row, int koff) {
    const float4* p = reinterpret_cast<const float4*>(A + row * DD + koff);
    float4 a = p[0], b = p[1];
    bf16x8 r;
    r[0] = f2bf(a.x); r[1] = f2bf(a.y); r[2] = f2bf(a.z); r[3] = f2bf(a.w);
    r[4] = f2bf(b.x); r[5] = f2bf(b.y); r[6] = f2bf(b.z); r[7] = f2bf(b.w);
    return r;
}

// ---------------- weight convert: bf16 + PRE-SWIZZLE (+ W_msg transpose) ------------
__global__ __launch_bounds__(256) void wconv(
    const float* __restrict__ W_in, const float* __restrict__ W_msg,
    const float* __restrict__ W_ih, const float* __restrict__ W_hh,
    const float* __restrict__ W_out, unsigned short* __restrict__ wb,
    int* __restrict__ gcur)
{
    int i = blockIdx.x * 256 + threadIdx.x;
    if (i < 147456) {
        int slice = i >> 14;
        int r = i & 16383;
        int n = r >> 7, k = r & 127;
        float v;
        if (slice == 0)      v = W_in[r];
        else if (slice == 1) v = W_msg[k * DD + n];          // transpose
        else if (slice <= 4) v = W_ih[(slice - 2) * 16384 + r];
        else if (slice <= 7) v = W_hh[(slice - 5) * 16384 + r];
        else                 v = W_out[r];
        wb[(i & ~16383) + n * 128 + (((k >> 3) ^ (n & 15)) << 3) + (k & 7)] = f2bf(v);
    } else if (i < 149504) {
        gcur[i - 147456] = 0;   // 2048 ints: 1563 bin counters + govf + pad
    }
}

// ============ bin_edges body: bin edges by dst>>6 (64-row bins), LDS write-combined ==
__device__ void bin_edges_body(char* smem, int bid,
    const int* __restrict__ ei, int E, int nbc,
    unsigned int* __restrict__ bucket, int* __restrict__ gcur,
    int* __restrict__ govf, unsigned long long* __restrict__ ovf)
{
    unsigned int (*ring)[RING] = (unsigned int (*)[RING])smem;            // 51200B
    int* lres = (int*)(smem + MAXB * RING * 4);                           // 6400B
    int* lfl  = lres + MAXB;                                              // 6400B
    const int tid = threadIdx.x;
    for (int b = tid; b < MAXB; b += 256) { lres[b] = 0; lfl[b] = 0; }
    __syncthreads();

    const int nt = (E + 255) >> 8;
    for (int t = bid; t < nt; t += NBIN_BLOCKS) {
        const int e = (t << 8) + tid;
        if (e < E) {
            const int d = ei[E + e];
            const int s = ei[e];
            const int b = d >> 6;
            const unsigned int ent = ((unsigned int)s << 8) | (unsigned int)(d & 63);
            const int pos = atomicAdd(&lres[b], 1);
            if (pos - lfl[b] >= RING) {
                const int op = atomicAdd(govf, 1);
                ovf[op] = ((unsigned long long)(unsigned int)s << 32) | (unsigned int)d;
            } else {
                ring[b][pos & (RING - 1)] = ent;
            }
        }
        __syncthreads();
        for (int bb = tid; bb < nbc; bb += 256) {
            const int res = lres[bb];
            const int fl = lfl[bb];
            const int lim = fl + RING;
            const bool drain = res > lim;
            const int hi = drain ? lim : res;
            const int avail = hi - fl;
            const int nf = drain ? avail : (avail & ~7);
            if (nf > 0) {
                const int gp = atomicAdd(&gcur[bb], nf);
                unsigned int* dst = bucket + ((size_t)bb << CAPSH) + gp;
                for (int k = 0; k < nf; ++k) dst[k] = ring[bb][(fl + k) & (RING - 1)];
            }
            lfl[bb] = drain ? res : fl + nf;
        }
        __syncthreads();
    }
    for (int bb = tid; bb < nbc; bb += 256) {
        const int res = lres[bb];
        const int fl = lfl[bb];
        const int avail = res - fl;
        if (avail > 0) {
            const int gp = atomicAdd(&gcur[bb], avail);
            unsigned int* dst = bucket + ((size_t)bb << CAPSH) + gp;
            for (int k = 0; k < avail; ++k) dst[k] = ring[bb][(fl + k) & (RING - 1)];
        }
    }
}

// ============ k12 body: h = x@W_in^T + b_in ; m = h@W_msg (fused) ============
__device__ void k12_body(char* smem, int bid,
    const float* __restrict__ x, const unsigned short* __restrict__ Wi,
    const unsigned short* __restrict__ Wm, const float* __restrict__ b_in,
    unsigned short* __restrict__ h_bf, unsigned short* __restrict__ m_bf, int M)
{
    float4* WA = (float4*)smem;             // 32KB: W_in, then h tile (overlay)
    float4* WB = (float4*)(smem + 32768);   // 32KB: W_msgT
    const int tid = threadIdx.x;
    const int lane = tid & 63;
    const int w = tid >> 6;
    const int c15 = lane & 15;
    const int hi = lane >> 4;
    const long base = (long)bid * 64;
    long arow = base + w * 16 + c15;
    if (arow >= M) arow = M - 1;

    copyW(WA, Wi, tid);
    copyW(WB, Wm, tid);
    __syncthreads();

    f32x4 acc[8];
#pragma unroll
    for (int ct = 0; ct < 8; ++ct) acc[ct] = (f32x4){0.f, 0.f, 0.f, 0.f};
#pragma unroll 1
    for (int s = 0; s < 4; ++s) {
        bf16x8 a = fragGF(x, arow, s * 32 + 8 * hi);
#pragma unroll
        for (int ct = 0; ct < 8; ++ct)
            acc[ct] = MFMA16(a, fragL(WA, lane, s, ct * 16 + c15), acc[ct]);
    }
    __syncthreads();

    unsigned short* Hu = reinterpret_cast<unsigned short*>(WA);
#pragma unroll
    for (int ct = 0; ct < 8; ++ct)
#pragma unroll
        for (int j = 0; j < 4; ++j) {
            int rloc = w * 16 + 4 * hi + j;
            long r = base + rloc;
            int c = ct * 16 + c15;
            float v = acc[ct][j] + b_in[c];
            unsigned short hv = f2bf(v);
            Hu[rloc * DD + (((c >> 3) ^ (rloc & 15)) << 3) + (c & 7)] = hv;
            if (r < M) h_bf[r * DD + c] = hv;
        }
    __syncthreads();

#pragma unroll
    for (int ct = 0; ct < 8; ++ct) acc[ct] = (f32x4){0.f, 0.f, 0.f, 0.f};
#pragma unroll 1
    for (int s = 0; s < 4; ++s) {
        bf16x8 a = fragL(WA, lane, s, w * 16 + c15);
#pragma unroll
        for (int ct = 0; ct < 8; ++ct)
            acc[ct] = MFMA16(a, fragL(WB, lane, s, ct * 16 + c15), acc[ct]);
    }
#pragma unroll
    for (int ct = 0; ct < 8; ++ct)
#pragma unroll
        for (int j = 0; j < 4; ++j) {
            long r = base + w * 16 + 4 * hi + j;
            if (r < M) m_bf[r * DD + ct * 16 + c15] = f2bf(acc[ct][j]);
        }
}

// ============ front: blockIdx-dispatched {bin_edges || k12} ============
__global__ __launch_bounds__(256) void front(
    const int* __restrict__ ei, int E, int nbc,
    unsigned int* __restrict__ bucket, int* __restrict__ gcur,
    int* __restrict__ govf, unsigned long long* __restrict__ ovf,
    const float* __restrict__ x, const unsigned short* __restrict__ Wi,
    const unsigned short* __restrict__ Wm, const float* __restrict__ b_in,
    unsigned short* __restrict__ h_bf, unsigned short* __restrict__ m_bf, int M)
{
    __shared__ float4 smem4[4096];   // 64KB, 16B-aligned
    char* smem = (char*)smem4;
    if (blockIdx.x < NBIN_BLOCKS)
        bin_edges_body(smem, blockIdx.x, ei, E, nbc, bucket, gcur, govf, ovf);
    else
        k12_body(smem, blockIdx.x - NBIN_BLOCKS, x, Wi, Wm, b_in, h_bf, m_bf, M);
}

// ============ bin_reduce: per-32-dst-row block over 64-row bins (2 sub-blocks) ======
// R16: bins are 64 rows -> each block scans ~1024 entries (was 4096), 2x scan
// redundancy (was 8x). Phase A/B machinery identical to the proven R12 kernel.
// XCD remap: a bin's 2 sub-blocks share p%8 -> same XCD L2.
__global__ __launch_bounds__(256, 8) void bin_reduce(
    const unsigned short* __restrict__ m,
    const unsigned int* __restrict__ bucket, const int* __restrict__ gcur,
    const int* __restrict__ govf, const unsigned long long* __restrict__ ovf,
    unsigned short* __restrict__ agg, int N, int nbc)
{
    __shared__ float acc[32 * DD];             // 16KB
    __shared__ unsigned int wlist[4][WCAP];    // 3968B
    const int tid = threadIdx.x, lane = tid & 63, wv = tid >> 6;
    const int p = blockIdx.x;
    const int cb = (p & 7) + ((p >> 4) << 3);  // same p%8 for both q of a bin
    const int q = (p >> 3) & 1;
    if (cb >= nbc) return;

    {
        float4* a4 = (float4*)acc;
        const float4 z = {0.f, 0.f, 0.f, 0.f};
        for (int i = tid; i < 32 * DD / 4; i += 256) a4[i] = z;
    }

    int cnt = gcur[cb];
    if (cnt > (1 << CAPSH)) cnt = 1 << CAPSH;
    const unsigned int* bb = bucket + ((size_t)cb << CAPSH);

    // ---- Phase A: compact this wave's entries (dl>>5==q, dl&3==wv) ----
    int nw = 0;
    bool ovfw = false;
    for (int c0 = 0; c0 < cnt; c0 += 64) {
        const int idx = c0 + lane;
        const unsigned int ent = (idx < cnt) ? bb[idx] : 0u;
        const int dl = ent & 255;                 // 0..63
        const bool mine = (idx < cnt) && ((dl >> 5) == q) && ((dl & 3) == wv);
        const unsigned long long mask = __ballot(mine);
        if (mine) {
            const int p2 = __popcll(mask & ((1ull << lane) - 1));
            const int pos = nw + p2;
            if (pos < WCAP) wlist[wv][pos] = ent;
            else ovfw = true;
        }
        nw += __popcll(mask);
    }
    const int nmy = (nw < WCAP) ? nw : WCAP;
    __syncthreads();

    // ---- Phase B: 8 named independent gathers per iteration ----
    const unsigned int* mu = (const unsigned int*)m;   // row stride 64 u32
    int i = 0;
    for (; i + 8 <= nmy; i += 8) {
        const unsigned int e0 = wlist[wv][i + 0], e1 = wlist[wv][i + 1];
        const unsigned int e2 = wlist[wv][i + 2], e3 = wlist[wv][i + 3];
        const unsigned int e4 = wlist[wv][i + 4], e5 = wlist[wv][i + 5];
        const unsigned int e6 = wlist[wv][i + 6], e7 = wlist[wv][i + 7];
        const unsigned int v0 = mu[(size_t)(e0 >> 8) * 64 + lane];
        const unsigned int v1 = mu[(size_t)(e1 >> 8) * 64 + lane];
        const unsigned int v2 = mu[(size_t)(e2 >> 8) * 64 + lane];
        const unsigned int v3 = mu[(size_t)(e3 >> 8) * 64 + lane];
        const unsigned int v4 = mu[(size_t)(e4 >> 8) * 64 + lane];
        const unsigned int v5 = mu[(size_t)(e5 >> 8) * 64 + lane];
        const unsigned int v6 = mu[(size_t)(e6 >> 8) * 64 + lane];
        const unsigned int v7 = mu[(size_t)(e7 >> 8) * 64 + lane];
        float2* p3;
        float2 a;
#define RMW(EE, VV) \
        p3 = (float2*)&acc[((EE) & 31) * DD + lane * 2]; a = *p3; \
        a.x += bf2f((unsigned short)((VV) & 0xffff)); \
        a.y += bf2f((unsigned short)((VV) >> 16)); *p3 = a;
        RMW(e0, v0) RMW(e1, v1) RMW(e2, v2) RMW(e3, v3)
        RMW(e4, v4) RMW(e5, v5) RMW(e6, v6) RMW(e7, v7)
    }
    for (; i < nmy; ++i) {
        const unsigned int e0 = wlist[wv][i];
        const unsigned int v0 = mu[(size_t)(e0 >> 8) * 64 + lane];
        float2* p3;
        float2 a;
        RMW(e0, v0)
    }
#undef RMW

    // ---- rare: list overflow fallback (ordinals >= WCAP) ----
    if (__ballot(ovfw)) {
        if (ovfw) {
            int cum = 0;
            for (int c0 = 0; c0 < cnt; c0 += 64) {
                const int idx = c0 + lane;
                const unsigned int ent = (idx < cnt) ? bb[idx] : 0u;
                const int dl = ent & 255;
                const bool mine = (idx < cnt) && ((dl >> 5) == q) && ((dl & 3) == wv);
                unsigned long long mask = __ballot(mine);
                unsigned long long mm = mask;
                int k = 0;
                while (mm) {
                    const int l = __builtin_ctzll(mm); mm &= mm - 1;
                    if (cum + k >= WCAP) {
                        const unsigned int ee = __shfl(ent, l);
                        const unsigned int vv = mu[(size_t)(ee >> 8) * 64 + lane];
                        float2* p3 = (float2*)&acc[(ee & 31) * DD + lane * 2];
                        float2 a = *p3;
                        a.x += bf2f((unsigned short)(vv & 0xffff));
                        a.y += bf2f((unsigned short)(vv >> 16));
                        *p3 = a;
                    }
                    ++k;
                }
                cum += __popcll(mask);
            }
        }
    }

    // ---- rare: ring-overflow entries from bin_edges ----
    const int novf = *govf;
    for (int i2 = 0; i2 < novf; ++i2) {
        const unsigned long long v = ovf[i2];
        const int d = (int)(v & 0xffffffffu);
        if ((d >> 6) != cb) continue;
        const int dl = d & 63;
        if ((dl >> 5) != q || (dl & 3) != wv) continue;
        const int src = (int)(v >> 32);
        const unsigned int vv = mu[(size_t)src * 64 + lane];
        float2* p3 = (float2*)&acc[(dl & 31) * DD + lane * 2];
        float2 a = *p3;
        a.x += bf2f((unsigned short)(vv & 0xffff));
        a.y += bf2f((unsigned short)(vv >> 16));
        *p3 = a;
    }
    __syncthreads();

    const long rbase = (long)cb * 64 + (long)q * 32;
    for (int r = wv; r < 32; r += 4) {
        const long rg = rbase + r;
        if (rg < N) {
            const float a0 = acc[r * DD + lane * 2];
            const float a1 = acc[r * DD + lane * 2 + 1];
            const unsigned int pk = ((unsigned int)f2bf(a1) << 16) | f2bf(a0);
            *(unsigned int*)(agg + rg * DD + lane * 2) = pk;
        }
    }
}

// ---------------- gru8 v5 (R10/R12 proven): R6 dual-buffer tile schedule ----------
__global__ __launch_bounds__(256, 2) void gru8(
    const unsigned short* __restrict__ agg, const unsigned short* __restrict__ hbf,
    const unsigned short* __restrict__ Wih, const unsigned short* __restrict__ Whh,
    const unsigned short* __restrict__ Wo,
    const float* __restrict__ b_ih, const float* __restrict__ b_hh,
    const float* __restrict__ b_out, float* __restrict__ out, int M)
{
    __shared__ float4 WA[2048];      // 32KB: W_ih gate stage, then Htile overlay
    __shared__ float4 WB[2048];      // 32KB: W_hh gate stage, then Wo
    const int tid = threadIdx.x;
    const int lane = tid & 63;
    const int w = tid >> 6;
    const int c15 = lane & 15;
    const int hi = lane >> 4;
    const long base = (long)blockIdx.x * 64;
    long arow = base + w * 16 + c15;
    if (arow >= M) arow = M - 1;

    // cached A-fragments (agg and h), used by all three gates
    bf16x8 ai[4], ah[4];
#pragma unroll
    for (int s = 0; s < 4; ++s) {
        ai[s] = fragG(agg, arow, s * 32 + 8 * hi);
        ah[s] = fragG(hbf, arow, s * 32 + 8 * hi);
    }

    f32x4 acc[8], acch[8];
    unsigned int rgp[16], zgp[16];   // packed bf16 gate values

    // ---- gate r ----
    copyW(WA, Wih, tid);
    copyW(WB, Whh, tid);
    __syncthreads();
#pragma unroll
    for (int ct = 0; ct < 8; ++ct) acc[ct] = (f32x4){0.f, 0.f, 0.f, 0.f};
#pragma unroll
    for (int s = 0; s < 4; ++s)
#pragma unroll
        for (int ct = 0; ct < 8; ++ct)
            acc[ct] = MFMA16(ai[s], fragL(WA, lane, s, ct * 16 + c15), acc[ct]);
#pragma unroll
    for (int s = 0; s < 4; ++s)
#pragma unroll
        for (int ct = 0; ct < 8; ++ct)
            acc[ct] = MFMA16(ah[s], fragL(WB, lane, s, ct * 16 + c15), acc[ct]);
#pragma unroll
    for (int ct = 0; ct < 8; ++ct) {
        const int c = ct * 16 + c15;
        const float b = b_ih[c] + b_hh[c];
        const float v0 = fsig(acc[ct][0] + b), v1 = fsig(acc[ct][1] + b);
        const float v2 = fsig(acc[ct][2] + b), v3 = fsig(acc[ct][3] + b);
        rgp[ct * 2 + 0] = ((unsigned int)f2bf(v1) << 16) | f2bf(v0);
        rgp[ct * 2 + 1] = ((unsigned int)f2bf(v3) << 16) | f2bf(v2);
    }
    __syncthreads();

    // ---- gate z ----
    copyW(WA, Wih + 16384, tid);
    copyW(WB, Whh + 16384, tid);
    __syncthreads();
#pragma unroll
    for (int ct = 0; ct < 8; ++ct) acc[ct] = (f32x4){0.f, 0.f, 0.f, 0.f};
#pragma unroll
    for (int s = 0; s < 4; ++s)
#pragma unroll
        for (int ct = 0; ct < 8; ++ct)
            acc[ct] = MFMA16(ai[s], fragL(WA, lane, s, ct * 16 + c15), acc[ct]);
#pragma unroll
    for (int s = 0; s < 4; ++s)
#pragma unroll
        for (int ct = 0; ct < 8; ++ct)
            acc[ct] = MFMA16(ah[s], fragL(WB, lane, s, ct * 16 + c15), acc[ct]);
#pragma unroll
    for (int ct = 0; ct < 8; ++ct) {
        const int c = ct * 16 + c15;
        const float b = b_ih[DD + c] + b_hh[DD + c];
        const float v0 = fsig(acc[ct][0] + b), v1 = fsig(acc[ct][1] + b);
        const float v2 = fsig(acc[ct][2] + b), v3 = fsig(acc[ct][3] + b);
        zgp[ct * 2 + 0] = ((unsigned int)f2bf(v1) << 16) | f2bf(v0);
        zgp[ct * 2 + 1] = ((unsigned int)f2bf(v3) << 16) | f2bf(v2);
    }
    __syncthreads();

    // ---- gate n (separate i/h accumulators) ----
    copyW(WA, Wih + 32768, tid);
    copyW(WB, Whh + 32768, tid);
    __syncthreads();
#pragma unroll
    for (int ct = 0; ct < 8; ++ct) {
        acc[ct] = (f32x4){0.f, 0.f, 0.f, 0.f};
        acch[ct] = (f32x4){0.f, 0.f, 0.f, 0.f};
    }
#pragma unroll
    for (int s = 0; s < 4; ++s)
#pragma unroll
        for (int ct = 0; ct < 8; ++ct)
            acc[ct] = MFMA16(ai[s], fragL(WA, lane, s, ct * 16 + c15), acc[ct]);
#pragma unroll
    for (int s = 0; s < 4; ++s)
#pragma unroll
        for (int ct = 0; ct < 8; ++ct)
            acch[ct] = MFMA16(ah[s], fragL(WB, lane, s, ct * 16 + c15), acch[ct]);
    __syncthreads();   // all waves done reading WA/WB

    // ---- GRU combine -> Htile (overlay WA); stage Wo -> WB ----
    unsigned short* Hu = reinterpret_cast<unsigned short*>(WA);
#pragma unroll
    for (int ct = 0; ct < 8; ++ct) {
        const int c = ct * 16 + c15;
        const float bi = b_ih[2 * DD + c], bh = b_hh[2 * DD + c];
#pragma unroll
        for (int j = 0; j < 4; ++j) {
            const int rloc = w * 16 + 4 * hi + j;
            long rr = base + rloc;
            if (rr >= M) rr = M - 1;
            const float r = bf2f((unsigned short)(rgp[ct * 2 + (j >> 1)] >> ((j & 1) * 16)));
            const float z = bf2f((unsigned short)(zgp[ct * 2 + (j >> 1)] >> ((j & 1) * 16)));
            const float n = ftanh(acc[ct][j] + bi + r * (acch[ct][j] + bh));
            const float hv = bf2f(hbf[rr * DD + c]);
            const float hnew = (1.f - z) * n + z * hv;
            Hu[rloc * DD + (((c >> 3) ^ (rloc & 15)) << 3) + (c & 7)] = f2bf(hnew);
        }
    }
    copyW(WB, Wo, tid);
    __syncthreads();

    // ---- out = h_new @ W_out^T + b_out ----
#pragma unroll
    for (int ct = 0; ct < 8; ++ct) acc[ct] = (f32x4){0.f, 0.f, 0.f, 0.f};
#pragma unroll
    for (int s = 0; s < 4; ++s) {
        bf16x8 a = fragL(WA, lane, s, w * 16 + c15);
#pragma unroll
        for (int ct = 0; ct < 8; ++ct)
            acc[ct] = MFMA16(a, fragL(WB, lane, s, ct * 16 + c15), acc[ct]);
    }
#pragma unroll
    for (int ct = 0; ct < 8; ++ct)
#pragma unroll
        for (int j = 0; j < 4; ++j) {
            long r = base + w * 16 + 4 * hi + j;
            if (r < M) out[r * DD + ct * 16 + c15] = acc[ct][j] + b_out[ct * 16 + c15];
        }
}

extern "C" void kernel_launch(void* const* d_in, const int* in_sizes, int n_in,
                              void* d_out, int out_size, void* d_ws, size_t ws_size,
                              hipStream_t stream) {
    const float* x     = (const float*)d_in[0];
    const int*   ei    = (const int*)d_in[1];
    const float* W_in  = (const float*)d_in[2];
    const float* b_in  = (const float*)d_in[3];
    const float* W_msg = (const float*)d_in[4];
    const float* W_ih  = (const float*)d_in[5];
    const float* b_ih  = (const float*)d_in[6];
    const float* W_hh  = (const float*)d_in[7];
    const float* b_hh  = (const float*)d_in[8];
    const float* W_out = (const float*)d_in[9];
    const float* b_out = (const float*)d_in[10];

    const int N = in_sizes[0] / DD;     // 100000
    const int E = in_sizes[1] / 2;      // 1600000
    float* out = (float*)d_out;

    // ws: 512KB weights (pre-swizzled) | h_bf | m_bf | agg_bf
    const size_t slotE = (size_t)N * DD;
    unsigned short* wb     = (unsigned short*)d_ws;
    unsigned short* h_bf   = (unsigned short*)((char*)d_ws + (1 << 19));
    unsigned short* m_bf   = h_bf + slotE;
    unsigned short* agg_bf = m_bf + slotE;

    // bin scratch in d_out (dead until gru8 writes out at the very end):
    // bucket @0 (1563<<11 u32 = 12.8MB) | gcur[2048] @16MB (zeroed by wconv) |
    // govf = gcur+2040 | ovf u64[8192] @gcur+2048
    const int nbc = (N + 63) >> 6;      // 1563 (64-row bins)
    unsigned int* bucket = (unsigned int*)d_out;
    int* gcur = (int*)((char*)d_out + (16u << 20));
    int* govf = gcur + 2040;
    unsigned long long* ovf = (unsigned long long*)(gcur + 2048);

    dim3 blk(256);
    const int gblocks = (N + 63) / 64;           // 1563 (front/k12, gru8)
    const int brblocks = 16 * ((nbc + 7) / 8);   // 3136 (bin_reduce remapped grid)

    wconv<<<(149504 + 255) / 256, blk, 0, stream>>>(W_in, W_msg, W_ih, W_hh, W_out, wb, gcur);
    front<<<NBIN_BLOCKS + gblocks, blk, 0, stream>>>(ei, E, nbc, bucket, gcur, govf, ovf,
                                                     x, wb, wb + 16384, b_in, h_bf, m_bf, N);
    bin_reduce<<<brblocks, blk, 0, stream>>>(m_bf, bucket, gcur, govf, ovf, agg_bf, N, nbc);
    gru8<<<gblocks, blk, 0, stream>>>(agg_bf, h_bf, wb + 32768, wb + 81920, wb + 131072,
                                      b_ih, b_hh, b_out, out, N);
}

// Round 18
// 228.558 us; speedup vs baseline: 3.0710x; 3.0710x over previous
//
#include <hip/hip_runtime.h>
#include <math.h>

#define DD 128
#define RING 32
#define MAXB 400      // >= nbc = ceil(N/256)
#define CAPSH 13      // 8192 entries per coarse bin (avg 4092 for this dataset)
#define WCAP 248      // per-wave compacted list capacity (expected ~128)
#define NBIN_BLOCKS 256

using bf16x8 = __attribute__((ext_vector_type(8))) short;
using f32x4  = __attribute__((ext_vector_type(4))) float;

__device__ inline unsigned short f2bf(float f) {
    unsigned int u = __float_as_uint(f);
    unsigned int r = (u + 0x7fffu + ((u >> 16) & 1u)) >> 16;   // RNE
    return (unsigned short)r;
}
__device__ inline float bf2f(unsigned short h) {
    return __uint_as_float(((unsigned int)h) << 16);
}
__device__ inline float fsig(float v) {            // sigmoid via rcp (no v_div)
    return __builtin_amdgcn_rcpf(1.f + __expf(-v));
}
__device__ inline float ftanh(float v) {           // tanh via exp+rcp (no libm)
    float x = fminf(15.f, fmaxf(-15.f, v));
    float t = __expf(2.f * x);
    return (t - 1.f) * __builtin_amdgcn_rcpf(t + 1.f);
}

#define MFMA16(a, b, c) __builtin_amdgcn_mfma_f32_16x16x32_bf16((a), (b), (c), 0, 0, 0)

// Weights are stored PRE-SWIZZLED in wb (fragL order): staging = linear copy.
__device__ inline void copyW(float4* dst, const unsigned short* W, int tid) {
    const float4* s4 = reinterpret_cast<const float4*>(W);
#pragma unroll
    for (int it = 0; it < 8; ++it) dst[tid + it * 256] = s4[tid + it * 256];
}

// Fragment read from swizzled LDS matrix: row r, k-slice s.
__device__ inline bf16x8 fragL(const float4* lds, int lane, int s, int r) {
    float4 v = lds[r * 16 + (((s << 2) + (lane >> 4)) ^ (r & 15))];
    return __builtin_bit_cast(bf16x8, v);
}

__device__ inline bf16x8 fragG(const unsigned short* A, long row, int koff) {
    float4 v = *reinterpret_cast<const float4*>(A + row * DD + koff);
    return __builtin_bit_cast(bf16x8, v);
}

__device__ inline bf16x8 fragGF(const float* A, long row, int koff) {
    const float4* p = reinterpret_cast<const float4*>(A + row * DD + koff);
    float4 a = p[0], b = p[1];
    bf16x8 r;
    r[0] = f2bf(a.x); r[1] = f2bf(a.y); r[2] = f2bf(a.z); r[3] = f2bf(a.w);
    r[4] = f2bf(b.x); r[5] = f2bf(b.y); r[6] = f2bf(b.z); r[7] = f2bf(b.w);
    return r;
}

// ---------------- weight convert: bf16 + PRE-SWIZZLE (+ W_msg transpose) ------------
__global__ __launch_bounds__(256) void wconv(
    const float* __restrict__ W_in, const float* __restrict__ W_msg,
    const float* __restrict__ W_ih, const float* __restrict__ W_hh,
    const float* __restrict__ W_out, unsigned short* __restrict__ wb,
    int* __restrict__ gcur)
{
    int i = blockIdx.x * 256 + threadIdx.x;
    if (i < 147456) {
        int slice = i >> 14;
        int r = i & 16383;
        int n = r >> 7, k = r & 127;
        float v;
        if (slice == 0)      v = W_in[r];
        else if (slice == 1) v = W_msg[k * DD + n];          // transpose
        else if (slice <= 4) v = W_ih[(slice - 2) * 16384 + r];
        else if (slice <= 7) v = W_hh[(slice - 5) * 16384 + r];
        else                 v = W_out[r];
        wb[(i & ~16383) + n * 128 + (((k >> 3) ^ (n & 15)) << 3) + (k & 7)] = f2bf(v);
    } else if (i < 148480) {
        gcur[i - 147456] = 0;
    }
}

// ============ bin_edges body: bin edges by dst>>8, LDS write-combined ============
__device__ void bin_edges_body(char* smem, int bid,
    const int* __restrict__ ei, int E, int nbc,
    unsigned int* __restrict__ bucket, int* __restrict__ gcur,
    int* __restrict__ govf, unsigned long long* __restrict__ ovf)
{
    unsigned int (*ring)[RING] = (unsigned int (*)[RING])smem;            // 51200B
    int* lres = (int*)(smem + MAXB * RING * 4);                           // 1600B
    int* lfl  = lres + MAXB;                                              // 1600B
    const int tid = threadIdx.x;
    for (int b = tid; b < MAXB; b += 256) { lres[b] = 0; lfl[b] = 0; }
    __syncthreads();

    const int nt = (E + 255) >> 8;
    for (int t = bid; t < nt; t += NBIN_BLOCKS) {
        const int e = (t << 8) + tid;
        if (e < E) {
            const int d = ei[E + e];
            const int s = ei[e];
            const int b = d >> 8;
            const unsigned int ent = ((unsigned int)s << 8) | (unsigned int)(d & 255);
            const int pos = atomicAdd(&lres[b], 1);
            if (pos - lfl[b] >= RING) {
                const int op = atomicAdd(govf, 1);
                ovf[op] = ((unsigned long long)(unsigned int)s << 32) | (unsigned int)d;
            } else {
                ring[b][pos & (RING - 1)] = ent;
            }
        }
        __syncthreads();
        for (int bb = tid; bb < nbc; bb += 256) {
            const int res = lres[bb];
            const int fl = lfl[bb];
            const int lim = fl + RING;
            const bool drain = res > lim;
            const int hi = drain ? lim : res;
            const int avail = hi - fl;
            const int nf = drain ? avail : (avail & ~15);
            if (nf > 0) {
                const int gp = atomicAdd(&gcur[bb], nf);
                unsigned int* dst = bucket + ((size_t)bb << CAPSH) + gp;
                for (int k = 0; k < nf; ++k) dst[k] = ring[bb][(fl + k) & (RING - 1)];
            }
            lfl[bb] = drain ? res : fl + nf;
        }
        __syncthreads();
    }
    for (int bb = tid; bb < nbc; bb += 256) {
        const int res = lres[bb];
        const int fl = lfl[bb];
        const int avail = res - fl;
        if (avail > 0) {
            const int gp = atomicAdd(&gcur[bb], avail);
            unsigned int* dst = bucket + ((size_t)bb << CAPSH) + gp;
            for (int k = 0; k < avail; ++k) dst[k] = ring[bb][(fl + k) & (RING - 1)];
        }
    }
}

// ============ k12 body: h = x@W_in^T + b_in ; m = h@W_msg (fused) ============
__device__ void k12_body(char* smem, int bid,
    const float* __restrict__ x, const unsigned short* __restrict__ Wi,
    const unsigned short* __restrict__ Wm, const float* __restrict__ b_in,
    unsigned short* __restrict__ h_bf, unsigned short* __restrict__ m_bf, int M)
{
    float4* WA = (float4*)smem;             // 32KB: W_in, then h tile (overlay)
    float4* WB = (float4*)(smem + 32768);   // 32KB: W_msgT
    const int tid = threadIdx.x;
    const int lane = tid & 63;
    const int w = tid >> 6;
    const int c15 = lane & 15;
    const int hi = lane >> 4;
    const long base = (long)bid * 64;
    long arow = base + w * 16 + c15;
    if (arow >= M) arow = M - 1;

    copyW(WA, Wi, tid);
    copyW(WB, Wm, tid);
    __syncthreads();

    f32x4 acc[8];
#pragma unroll
    for (int ct = 0; ct < 8; ++ct) acc[ct] = (f32x4){0.f, 0.f, 0.f, 0.f};
#pragma unroll 1
    for (int s = 0; s < 4; ++s) {
        bf16x8 a = fragGF(x, arow, s * 32 + 8 * hi);
#pragma unroll
        for (int ct = 0; ct < 8; ++ct)
            acc[ct] = MFMA16(a, fragL(WA, lane, s, ct * 16 + c15), acc[ct]);
    }
    __syncthreads();

    unsigned short* Hu = reinterpret_cast<unsigned short*>(WA);
#pragma unroll
    for (int ct = 0; ct < 8; ++ct)
#pragma unroll
        for (int j = 0; j < 4; ++j) {
            int rloc = w * 16 + 4 * hi + j;
            long r = base + rloc;
            int c = ct * 16 + c15;
            float v = acc[ct][j] + b_in[c];
            unsigned short hv = f2bf(v);
            Hu[rloc * DD + (((c >> 3) ^ (rloc & 15)) << 3) + (c & 7)] = hv;
            if (r < M) h_bf[r * DD + c] = hv;
        }
    __syncthreads();

#pragma unroll
    for (int ct = 0; ct < 8; ++ct) acc[ct] = (f32x4){0.f, 0.f, 0.f, 0.f};
#pragma unroll 1
    for (int s = 0; s < 4; ++s) {
        bf16x8 a = fragL(WA, lane, s, w * 16 + c15);
#pragma unroll
        for (int ct = 0; ct < 8; ++ct)
            acc[ct] = MFMA16(a, fragL(WB, lane, s, ct * 16 + c15), acc[ct]);
    }
#pragma unroll
    for (int ct = 0; ct < 8; ++ct)
#pragma unroll
        for (int j = 0; j < 4; ++j) {
            long r = base + w * 16 + 4 * hi + j;
            if (r < M) m_bf[r * DD + ct * 16 + c15] = f2bf(acc[ct][j]);
        }
}

// ============ front: blockIdx-dispatched {bin_edges || k12} ============
__global__ __launch_bounds__(256) void front(
    const int* __restrict__ ei, int E, int nbc,
    unsigned int* __restrict__ bucket, int* __restrict__ gcur,
    int* __restrict__ govf, unsigned long long* __restrict__ ovf,
    const float* __restrict__ x, const unsigned short* __restrict__ Wi,
    const unsigned short* __restrict__ Wm, const float* __restrict__ b_in,
    unsigned short* __restrict__ h_bf, unsigned short* __restrict__ m_bf, int M)
{
    __shared__ float4 smem4[4096];   // 64KB, 16B-aligned
    char* smem = (char*)smem4;
    if (blockIdx.x < NBIN_BLOCKS)
        bin_edges_body(smem, blockIdx.x, ei, E, nbc, bucket, gcur, govf, ovf);
    else
        k12_body(smem, blockIdx.x - NBIN_BLOCKS, x, Wi, Wm, b_in, h_bf, m_bf, M);
}

// ============ bin_reduce (R12 proven): per-32-dst-row block, compacted-list gather ====
// XCD-aware remap: all 8 sub-blocks (q) of a coarse bin share p%8 -> same XCD
// under round-robin dispatch -> 8x-redundant bucket scans are same-L2 hits.
__global__ __launch_bounds__(256, 8) void bin_reduce(
    const unsigned short* __restrict__ m,
    const unsigned int* __restrict__ bucket, const int* __restrict__ gcur,
    const int* __restrict__ govf, const unsigned long long* __restrict__ ovf,
    unsigned short* __restrict__ agg, int N, int nbc)
{
    __shared__ float acc[32 * DD];             // 16KB
    __shared__ unsigned int wlist[4][WCAP];    // 3968B
    const int tid = threadIdx.x, lane = tid & 63, wv = tid >> 6;
    const int p = blockIdx.x;
    const int cb = (p & 7) + ((p >> 6) << 3);  // same p%8 for all q of a bin
    const int q = (p >> 3) & 7;
    if (cb >= nbc) return;

    {
        float4* a4 = (float4*)acc;
        const float4 z = {0.f, 0.f, 0.f, 0.f};
        for (int i = tid; i < 32 * DD / 4; i += 256) a4[i] = z;
    }

    int cnt = gcur[cb];
    if (cnt > (1 << CAPSH)) cnt = 1 << CAPSH;
    const unsigned int* bb = bucket + ((size_t)cb << CAPSH);

    // ---- Phase A: compact this wave's entries (dl>>5==q, dl&3==wv) ----
    int nw = 0;
    bool ovfw = false;
    for (int c0 = 0; c0 < cnt; c0 += 64) {
        const int idx = c0 + lane;
        const unsigned int ent = (idx < cnt) ? bb[idx] : 0u;
        const int dl = ent & 255;
        const bool mine = (idx < cnt) && ((dl >> 5) == q) && ((dl & 3) == wv);
        const unsigned long long mask = __ballot(mine);
        if (mine) {
            const int p2 = __popcll(mask & ((1ull << lane) - 1));
            const int pos = nw + p2;
            if (pos < WCAP) wlist[wv][pos] = ent;
            else ovfw = true;
        }
        nw += __popcll(mask);
    }
    const int nmy = (nw < WCAP) ? nw : WCAP;
    __syncthreads();

    // ---- Phase B: 8 named independent gathers per iteration ----
    const unsigned int* mu = (const unsigned int*)m;   // row stride 64 u32
    int i = 0;
    for (; i + 8 <= nmy; i += 8) {
        const unsigned int e0 = wlist[wv][i + 0], e1 = wlist[wv][i + 1];
        const unsigned int e2 = wlist[wv][i + 2], e3 = wlist[wv][i + 3];
        const unsigned int e4 = wlist[wv][i + 4], e5 = wlist[wv][i + 5];
        const unsigned int e6 = wlist[wv][i + 6], e7 = wlist[wv][i + 7];
        const unsigned int v0 = mu[(size_t)(e0 >> 8) * 64 + lane];
        const unsigned int v1 = mu[(size_t)(e1 >> 8) * 64 + lane];
        const unsigned int v2 = mu[(size_t)(e2 >> 8) * 64 + lane];
        const unsigned int v3 = mu[(size_t)(e3 >> 8) * 64 + lane];
        const unsigned int v4 = mu[(size_t)(e4 >> 8) * 64 + lane];
        const unsigned int v5 = mu[(size_t)(e5 >> 8) * 64 + lane];
        const unsigned int v6 = mu[(size_t)(e6 >> 8) * 64 + lane];
        const unsigned int v7 = mu[(size_t)(e7 >> 8) * 64 + lane];
        float2* p3;
        float2 a;
#define RMW(EE, VV) \
        p3 = (float2*)&acc[((EE) & 31) * DD + lane * 2]; a = *p3; \
        a.x += bf2f((unsigned short)((VV) & 0xffff)); \
        a.y += bf2f((unsigned short)((VV) >> 16)); *p3 = a;
        RMW(e0, v0) RMW(e1, v1) RMW(e2, v2) RMW(e3, v3)
        RMW(e4, v4) RMW(e5, v5) RMW(e6, v6) RMW(e7, v7)
    }
    for (; i < nmy; ++i) {
        const unsigned int e0 = wlist[wv][i];
        const unsigned int v0 = mu[(size_t)(e0 >> 8) * 64 + lane];
        float2* p3;
        float2 a;
        RMW(e0, v0)
    }
#undef RMW

    // ---- rare: list overflow fallback (ordinals >= WCAP) ----
    if (__ballot(ovfw)) {
        if (ovfw) {
            int cum = 0;
            for (int c0 = 0; c0 < cnt; c0 += 64) {
                const int idx = c0 + lane;
                const unsigned int ent = (idx < cnt) ? bb[idx] : 0u;
                const int dl = ent & 255;
                const bool mine = (idx < cnt) && ((dl >> 5) == q) && ((dl & 3) == wv);
                unsigned long long mask = __ballot(mine);
                unsigned long long mm = mask;
                int k = 0;
                while (mm) {
                    const int l = __builtin_ctzll(mm); mm &= mm - 1;
                    if (cum + k >= WCAP) {
                        const unsigned int ee = __shfl(ent, l);
                        const unsigned int vv = mu[(size_t)(ee >> 8) * 64 + lane];
                        float2* p3 = (float2*)&acc[(ee & 31) * DD + lane * 2];
                        float2 a = *p3;
                        a.x += bf2f((unsigned short)(vv & 0xffff));
                        a.y += bf2f((unsigned short)(vv >> 16));
                        *p3 = a;
                    }
                    ++k;
                }
                cum += __popcll(mask);
            }
        }
    }

    // ---- rare: ring-overflow entries from bin_edges ----
    const int novf = *govf;
    for (int i2 = 0; i2 < novf; ++i2) {
        const unsigned long long v = ovf[i2];
        const int d = (int)(v & 0xffffffffu);
        if ((d >> 8) != cb) continue;
        const int dl = d & 255;
        if ((dl >> 5) != q || (dl & 3) != wv) continue;
        const int src = (int)(v >> 32);
        const unsigned int vv = mu[(size_t)src * 64 + lane];
        float2* p3 = (float2*)&acc[(dl & 31) * DD + lane * 2];
        float2 a = *p3;
        a.x += bf2f((unsigned short)(vv & 0xffff));
        a.y += bf2f((unsigned short)(vv >> 16));
        *p3 = a;
    }
    __syncthreads();

    const long rbase = (long)cb * 256 + (long)q * 32;
    for (int r = wv; r < 32; r += 4) {
        const long rg = rbase + r;
        if (rg < N) {
            const float a0 = acc[r * DD + lane * 2];
            const float a1 = acc[r * DD + lane * 2 + 1];
            const unsigned int pk = ((unsigned int)f2bf(a1) << 16) | f2bf(a0);
            *(unsigned int*)(agg + rg * DD + lane * 2) = pk;
        }
    }
}

// ---------------- gru8 v5 (R10/R12 proven): R6 dual-buffer tile schedule ----------
__global__ __launch_bounds__(256, 2) void gru8(
    const unsigned short* __restrict__ agg, const unsigned short* __restrict__ hbf,
    const unsigned short* __restrict__ Wih, const unsigned short* __restrict__ Whh,
    const unsigned short* __restrict__ Wo,
    const float* __restrict__ b_ih, const float* __restrict__ b_hh,
    const float* __restrict__ b_out, float* __restrict__ out, int M)
{
    __shared__ float4 WA[2048];      // 32KB: W_ih gate stage, then Htile overlay
    __shared__ float4 WB[2048];      // 32KB: W_hh gate stage, then Wo
    const int tid = threadIdx.x;
    const int lane = tid & 63;
    const int w = tid >> 6;
    const int c15 = lane & 15;
    const int hi = lane >> 4;
    const long base = (long)blockIdx.x * 64;
    long arow = base + w * 16 + c15;
    if (arow >= M) arow = M - 1;

    // cached A-fragments (agg and h), used by all three gates
    bf16x8 ai[4], ah[4];
#pragma unroll
    for (int s = 0; s < 4; ++s) {
        ai[s] = fragG(agg, arow, s * 32 + 8 * hi);
        ah[s] = fragG(hbf, arow, s * 32 + 8 * hi);
    }

    f32x4 acc[8], acch[8];
    unsigned int rgp[16], zgp[16];   // packed bf16 gate values

    // ---- gate r ----
    copyW(WA, Wih, tid);
    copyW(WB, Whh, tid);
    __syncthreads();
#pragma unroll
    for (int ct = 0; ct < 8; ++ct) acc[ct] = (f32x4){0.f, 0.f, 0.f, 0.f};
#pragma unroll
    for (int s = 0; s < 4; ++s)
#pragma unroll
        for (int ct = 0; ct < 8; ++ct)
            acc[ct] = MFMA16(ai[s], fragL(WA, lane, s, ct * 16 + c15), acc[ct]);
#pragma unroll
    for (int s = 0; s < 4; ++s)
#pragma unroll
        for (int ct = 0; ct < 8; ++ct)
            acc[ct] = MFMA16(ah[s], fragL(WB, lane, s, ct * 16 + c15), acc[ct]);
#pragma unroll
    for (int ct = 0; ct < 8; ++ct) {
        const int c = ct * 16 + c15;
        const float b = b_ih[c] + b_hh[c];
        const float v0 = fsig(acc[ct][0] + b), v1 = fsig(acc[ct][1] + b);
        const float v2 = fsig(acc[ct][2] + b), v3 = fsig(acc[ct][3] + b);
        rgp[ct * 2 + 0] = ((unsigned int)f2bf(v1) << 16) | f2bf(v0);
        rgp[ct * 2 + 1] = ((unsigned int)f2bf(v3) << 16) | f2bf(v2);
    }
    __syncthreads();

    // ---- gate z ----
    copyW(WA, Wih + 16384, tid);
    copyW(WB, Whh + 16384, tid);
    __syncthreads();
#pragma unroll
    for (int ct = 0; ct < 8; ++ct) acc[ct] = (f32x4){0.f, 0.f, 0.f, 0.f};
#pragma unroll
    for (int s = 0; s < 4; ++s)
#pragma unroll
        for (int ct = 0; ct < 8; ++ct)
            acc[ct] = MFMA16(ai[s], fragL(WA, lane, s, ct * 16 + c15), acc[ct]);
#pragma unroll
    for (int s = 0; s < 4; ++s)
#pragma unroll
        for (int ct = 0; ct < 8; ++ct)
            acc[ct] = MFMA16(ah[s], fragL(WB, lane, s, ct * 16 + c15), acc[ct]);
#pragma unroll
    for (int ct = 0; ct < 8; ++ct) {
        const int c = ct * 16 + c15;
        const float b = b_ih[DD + c] + b_hh[DD + c];
        const float v0 = fsig(acc[ct][0] + b), v1 = fsig(acc[ct][1] + b);
        const float v2 = fsig(acc[ct][2] + b), v3 = fsig(acc[ct][3] + b);
        zgp[ct * 2 + 0] = ((unsigned int)f2bf(v1) << 16) | f2bf(v0);
        zgp[ct * 2 + 1] = ((unsigned int)f2bf(v3) << 16) | f2bf(v2);
    }
    __syncthreads();

    // ---- gate n (separate i/h accumulators) ----
    copyW(WA, Wih + 32768, tid);
    copyW(WB, Whh + 32768, tid);
    __syncthreads();
#pragma unroll
    for (int ct = 0; ct < 8; ++ct) {
        acc[ct] = (f32x4){0.f, 0.f, 0.f, 0.f};
        acch[ct] = (f32x4){0.f, 0.f, 0.f, 0.f};
    }
#pragma unroll
    for (int s = 0; s < 4; ++s)
#pragma unroll
        for (int ct = 0; ct < 8; ++ct)
            acc[ct] = MFMA16(ai[s], fragL(WA, lane, s, ct * 16 + c15), acc[ct]);
#pragma unroll
    for (int s = 0; s < 4; ++s)
#pragma unroll
        for (int ct = 0; ct < 8; ++ct)
            acch[ct] = MFMA16(ah[s], fragL(WB, lane, s, ct * 16 + c15), acch[ct]);
    __syncthreads();   // all waves done reading WA/WB

    // ---- GRU combine -> Htile (overlay WA); stage Wo -> WB ----
    unsigned short* Hu = reinterpret_cast<unsigned short*>(WA);
#pragma unroll
    for (int ct = 0; ct < 8; ++ct) {
        const int c = ct * 16 + c15;
        const float bi = b_ih[2 * DD + c], bh = b_hh[2 * DD + c];
#pragma unroll
        for (int j = 0; j < 4; ++j) {
            const int rloc = w * 16 + 4 * hi + j;
            long rr = base + rloc;
            if (rr >= M) rr = M - 1;
            const float r = bf2f((unsigned short)(rgp[ct * 2 + (j >> 1)] >> ((j & 1) * 16)));
            const float z = bf2f((unsigned short)(zgp[ct * 2 + (j >> 1)] >> ((j & 1) * 16)));
            const float n = ftanh(acc[ct][j] + bi + r * (acch[ct][j] + bh));
            const float hv = bf2f(hbf[rr * DD + c]);
            const float hnew = (1.f - z) * n + z * hv;
            Hu[rloc * DD + (((c >> 3) ^ (rloc & 15)) << 3) + (c & 7)] = f2bf(hnew);
        }
    }
    copyW(WB, Wo, tid);
    __syncthreads();

    // ---- out = h_new @ W_out^T + b_out ----
#pragma unroll
    for (int ct = 0; ct < 8; ++ct) acc[ct] = (f32x4){0.f, 0.f, 0.f, 0.f};
#pragma unroll
    for (int s = 0; s < 4; ++s) {
        bf16x8 a = fragL(WA, lane, s, w * 16 + c15);
#pragma unroll
        for (int ct = 0; ct < 8; ++ct)
            acc[ct] = MFMA16(a, fragL(WB, lane, s, ct * 16 + c15), acc[ct]);
    }
#pragma unroll
    for (int ct = 0; ct < 8; ++ct)
#pragma unroll
        for (int j = 0; j < 4; ++j) {
            long r = base + w * 16 + 4 * hi + j;
            if (r < M) out[r * DD + ct * 16 + c15] = acc[ct][j] + b_out[ct * 16 + c15];
        }
}

extern "C" void kernel_launch(void* const* d_in, const int* in_sizes, int n_in,
                              void* d_out, int out_size, void* d_ws, size_t ws_size,
                              hipStream_t stream) {
    const float* x     = (const float*)d_in[0];
    const int*   ei    = (const int*)d_in[1];
    const float* W_in  = (const float*)d_in[2];
    const float* b_in  = (const float*)d_in[3];
    const float* W_msg = (const float*)d_in[4];
    const float* W_ih  = (const float*)d_in[5];
    const float* b_ih  = (const float*)d_in[6];
    const float* W_hh  = (const float*)d_in[7];
    const float* b_hh  = (const float*)d_in[8];
    const float* W_out = (const float*)d_in[9];
    const float* b_out = (const float*)d_in[10];

    const int N = in_sizes[0] / DD;     // 100000
    const int E = in_sizes[1] / 2;      // 1600000
    float* out = (float*)d_out;

    // ws: 512KB weights (pre-swizzled) | h_bf | m_bf | agg_bf
    const size_t slotE = (size_t)N * DD;
    unsigned short* wb     = (unsigned short*)d_ws;
    unsigned short* h_bf   = (unsigned short*)((char*)d_ws + (1 << 19));
    unsigned short* m_bf   = h_bf + slotE;
    unsigned short* agg_bf = m_bf + slotE;

    // bin scratch in d_out (dead until gru8 writes out at the very end)
    const int nbc = (N + 255) >> 8;     // 391
    unsigned int* bucket = (unsigned int*)d_out;
    int* gcur = (int*)((char*)d_out + (16u << 20));
    int* govf = gcur + 512;
    unsigned long long* ovf = (unsigned long long*)(gcur + 1024);

    dim3 blk(256);
    const int gblocks = (N + 63) / 64;          // 1563 (front/k12, gru8)
    const int brblocks = 64 * ((nbc + 7) / 8);  // 3136 (bin_reduce remapped grid)

    wconv<<<(148480 + 255) / 256, blk, 0, stream>>>(W_in, W_msg, W_ih, W_hh, W_out, wb, gcur);
    front<<<NBIN_BLOCKS + gblocks, blk, 0, stream>>>(ei, E, nbc, bucket, gcur, govf, ovf,
                                                     x, wb, wb + 16384, b_in, h_bf, m_bf, N);
    bin_reduce<<<brblocks, blk, 0, stream>>>(m_bf, bucket, gcur, govf, ovf, agg_bf, N, nbc);
    gru8<<<gblocks, blk, 0, stream>>>(agg_bf, h_bf, wb + 32768, wb + 81920, wb + 131072,
                                      b_ih, b_hh, b_out, out, N);
}